// Round 5
// baseline (53015.936 us; speedup 1.0000x reference)
//
#include <hip/hip_runtime.h>
#include <cstdint>

#define NROWS 10000
#define DIM   784
#define CAND  150
#define MOUT  10
#define KMAX  64
#define TOT_W 117600   // DIM*CAND
#define TOT_B 150
#define BR 64          // rows per block tile
#define BC 160         // padded candidate cols
#define KT 16          // k tile
#define NBLK 157       // grid blocks = ceil(10000/64)

// ---------------- Threefry-2x32 (exact JAX partitionable semantics) ----------------
#define RND_(r) { x0 += x1; x1 = (x1 << r) | (x1 >> (32 - r)); x1 ^= x0; }

__device__ __host__ inline void threefry2x32(uint32_t k0, uint32_t k1,
                                             uint32_t c0, uint32_t c1,
                                             uint32_t* o0, uint32_t* o1) {
  uint32_t ks2 = 0x1BD11BDAu ^ k0 ^ k1;
  uint32_t x0 = c0 + k0, x1 = c1 + k1;
  RND_(13) RND_(15) RND_(26) RND_(6)
  x0 += k1;  x1 += ks2 + 1u;
  RND_(17) RND_(29) RND_(16) RND_(24)
  x0 += ks2; x1 += k0 + 2u;
  RND_(13) RND_(15) RND_(26) RND_(6)
  x0 += k0;  x1 += k1 + 3u;
  RND_(17) RND_(29) RND_(16) RND_(24)
  x0 += k1;  x1 += ks2 + 4u;
  RND_(13) RND_(15) RND_(26) RND_(6)
  x0 += ks2; x1 += k0 + 5u;
  *o0 = x0; *o1 = x1;
}

__device__ inline float uni01(uint32_t bits) {
  uint32_t fb = (bits >> 9) | 0x3F800000u;
  return __uint_as_float(fb) - 1.0f;
}

__device__ inline float scale_of(int j) {
  return (j < 50) ? 0.5f : ((j < 100) ? 1.0f : 5.0f);
}

__device__ inline void split3(uint32_t& key0, uint32_t& key1,
                              uint32_t& kw0, uint32_t& kw1,
                              uint32_t& kb0, uint32_t& kb1) {
  uint32_t o0[3], o1[3];
#pragma unroll
  for (int t = 0; t < 3; ++t)
    threefry2x32(key0, key1, 0u, (uint32_t)t, &o0[t], &o1[t]);
  kw0 = o0[1]; kw1 = o1[1]; kb0 = o0[2]; kb1 = o1[2];
  key0 = o0[0]; key1 = o1[0];
}

__device__ inline void gen_wb(int b, int tid, uint32_t kw0, uint32_t kw1,
                              uint32_t kb0, uint32_t kb1,
                              float* __restrict__ Wr, float* __restrict__ br) {
  for (int f = b * 256 + tid; f < TOT_W + TOT_B; f += NBLK * 256) {
    if (f < TOT_W) {
      uint32_t o0, o1;
      threefry2x32(kw0, kw1, 0u, (uint32_t)f, &o0, &o1);
      float u = uni01(o0 ^ o1);
      int j = f % CAND;
      Wr[f] = scale_of(j) * (2.0f * u - 1.0f);
    } else {
      int g = f - TOT_W;
      uint32_t o0, o1;
      threefry2x32(kb0, kb1, 0u, (uint32_t)g, &o0, &o1);
      float u = uni01(o0 ^ o1);
      br[g] = scale_of(g) * (2.0f * u - 1.0f);
    }
  }
}

// ---------------- software grid barrier (agent scope, XCD-safe) ----------------
// bar[0] = arrive counter, bar[1] = generation. Zeroed by init kernel each call.
__device__ inline void gbar(unsigned* bar, unsigned* lgen) {
  __syncthreads();
  if (threadIdx.x == 0) {
    unsigned target = *lgen + 1u;
    __threadfence();   // release my block's prior writes
    unsigned a = __hip_atomic_fetch_add(&bar[0], 1u, __ATOMIC_ACQ_REL, __HIP_MEMORY_SCOPE_AGENT);
    if (a == NBLK - 1) {
      __hip_atomic_store(&bar[0], 0u, __ATOMIC_RELAXED, __HIP_MEMORY_SCOPE_AGENT);
      __hip_atomic_store(&bar[1], target, __ATOMIC_RELEASE, __HIP_MEMORY_SCOPE_AGENT);
    } else {
      while (__hip_atomic_load(&bar[1], __ATOMIC_ACQUIRE, __HIP_MEMORY_SCOPE_AGENT) < target)
        __builtin_amdgcn_s_sleep(2);
    }
    __threadfence();   // acquire everyone's writes
  }
  __syncthreads();
  *lgen += 1u;
}

__global__ __launch_bounds__(64) void init_bar_kern(unsigned* bar) {
  if (threadIdx.x < 2) bar[threadIdx.x] = 0u;
}

// ---------------- the one persistent kernel ----------------
__global__ __launch_bounds__(256) void scn_mega(
    const float* __restrict__ X, const float* __restrict__ Y,
    float* __restrict__ outW, float* __restrict__ outb, float* __restrict__ outBeta,
    float* __restrict__ h_col, float* __restrict__ Wr, float* __restrict__ br,
    float* __restrict__ e, float* __restrict__ Hm, float* __restrict__ Qm,
    float* __restrict__ Rm, float* __restrict__ QT, float* __restrict__ r1g,
    float* __restrict__ part1t, float* __restrict__ part2t, float* __restrict__ scal,
    unsigned* __restrict__ bar)
{
  __shared__ __align__(16) float smem[7680];
  __shared__ __align__(16) float smem2[640];
  const int b = blockIdx.x, tid = threadIdx.x;
  uint32_t key0 = 0u, key1 = 42u;
  unsigned lgen = 0u;
  int* const ibest_g = (int*)scal + 12;

  // ---- prologue: e = Y (block's rows), gen W/b for step 0 ----
  {
    int base = b * BR * MOUT;
    for (int idx = tid; idx < BR * MOUT; idx += 256) {
      int g = base + idx;
      if (g < NROWS * MOUT) e[g] = Y[g];
    }
    uint32_t kw0, kw1, kb0, kb1;
    split3(key0, key1, kw0, kw1, kb0, kb1);
    gen_wb(b, tid, kw0, kw1, kb0, kb1, Wr, br);
  }
  gbar(bar, &lgen);

  for (int k = 0; k < KMAX; ++k) {
    // ================= G: gemm  h = sigmoid(X@W+b), partials =================
    {
      float* Xt = smem;            // [KT][BR]
      float* Wt = smem + 1024;     // [KT][BC]
      float* red = smem;           // [4][BC*11] (aliases Xt/Wt after compute)
      float* et = smem2;           // [BR][MOUT]
      int ty = tid >> 5, tx = tid & 31;
      int row0 = b * BR;
      int nr = NROWS - row0; if (nr > BR) nr = BR;
      bool full = (nr == BR);

      for (int idx = tid; idx < BR * MOUT; idx += 256) {
        int r = idx / MOUT, c = idx - r * MOUT;
        et[idx] = (row0 + r < NROWS) ? e[(size_t)(row0 + r) * MOUT + c] : 0.f;
      }

      float bbv[5];
#pragma unroll
      for (int cl = 0; cl < 5; ++cl) {
        int c = tx + 32 * cl;
        bbv[cl] = (c < CAND) ? br[c] : 0.f;
      }

      float acc[8][5];
#pragma unroll
      for (int r = 0; r < 8; ++r)
#pragma unroll
        for (int cl = 0; cl < 5; ++cl) acc[r][cl] = 0.f;

      int rstage = tid >> 2;
      int qg = (tid & 3) * 4;
      int rclamp = rstage < nr ? rstage : nr - 1;
      const float* Xrow = X + (size_t)(row0 + rclamp) * DIM;

      for (int kk = 0; kk < DIM; kk += KT) {
        __syncthreads();
        float4 xv4 = *(const float4*)(Xrow + kk + qg);
        Xt[(qg + 0) * BR + rstage] = xv4.x;
        Xt[(qg + 1) * BR + rstage] = xv4.y;
        Xt[(qg + 2) * BR + rstage] = xv4.z;
        Xt[(qg + 3) * BR + rstage] = xv4.w;
        for (int idx = tid; idx < KT * BC; idx += 256) {
          int q = idx / BC, c = idx - q * BC;
          Wt[idx] = (c < CAND) ? Wr[(size_t)(kk + q) * CAND + c] : 0.f;
        }
        __syncthreads();
#pragma unroll
        for (int q = 0; q < KT; ++q) {
          float xv[8];
          *(float4*)&xv[0] = *(const float4*)&Xt[q * BR + ty * 8];
          *(float4*)&xv[4] = *(const float4*)&Xt[q * BR + ty * 8 + 4];
          float wv[5];
#pragma unroll
          for (int cl = 0; cl < 5; ++cl) wv[cl] = Wt[q * BC + tx + 32 * cl];
#pragma unroll
          for (int r = 0; r < 8; ++r)
#pragma unroll
            for (int cl = 0; cl < 5; ++cl)
              acc[r][cl] = fmaf(xv[r], wv[cl], acc[r][cl]);
        }
      }

      __syncthreads();   // Xt/Wt dead; red region reusable

#pragma unroll
      for (int cl = 0; cl < 5; ++cl) {
        int c = tx + 32 * cl;
        float hv[8];
#pragma unroll
        for (int r = 0; r < 8; ++r)
          hv[r] = 1.0f / (1.0f + expf(-(acc[r][cl] + bbv[cl])));
        if (c < CAND) {
          float* dst = h_col + (size_t)c * NROWS + row0 + ty * 8;
          if (full) {
            float4 a = {hv[0], hv[1], hv[2], hv[3]};
            float4 b4 = {hv[4], hv[5], hv[6], hv[7]};
            *(float4*)dst = a;
            *(float4*)(dst + 4) = b4;
          } else {
#pragma unroll
            for (int r = 0; r < 8; ++r)
              if (ty * 8 + r < nr) dst[r] = hv[r];
          }
        }
        float hh = 0.f, eth[10];
#pragma unroll
        for (int j = 0; j < 10; ++j) eth[j] = 0.f;
#pragma unroll
        for (int r = 0; r < 8; ++r) {
          if (full || ty * 8 + r < nr) {
            hh = fmaf(hv[r], hv[r], hh);
#pragma unroll
            for (int j = 0; j < 10; ++j) eth[j] = fmaf(et[(ty * 8 + r) * MOUT + j], hv[r], eth[j]);
          }
        }
        hh += __shfl_xor(hh, 32);
#pragma unroll
        for (int j = 0; j < 10; ++j) eth[j] += __shfl_xor(eth[j], 32);
        if (!(ty & 1) && c < CAND) {
          float* dstr = red + (ty >> 1) * 1760 + c * 11;
          dstr[0] = hh;
#pragma unroll
          for (int j = 0; j < 10; ++j) dstr[1 + j] = eth[j];
        }
      }
      __syncthreads();
      for (int idx = tid; idx < CAND * 11; idx += 256) {
        float s = red[idx] + red[1760 + idx] + red[3520 + idx] + red[5280 + idx];
        part1t[(size_t)idx * NBLK + b] = s;
      }
    }
    gbar(bar, &lgen);

    // ================= S: reduce part1, argmax, record W col / b (block 0) =================
    if (b == 0) {
      float* sums = smem;                 // [1650]
      float* sv = smem + 1664;            // [256]
      int* si = (int*)(smem + 1920);      // [256]
      for (int idx = tid; idx < CAND * 11; idx += 256) {
        float s = 0.f;
        const float* p = part1t + (size_t)idx * NBLK;
        for (int b2 = 0; b2 < NBLK; ++b2) s += p[b2];
        sums[idx] = s;
      }
      __syncthreads();
      float v = -INFINITY; int bi = 0x7FFFFFFF;
      if (tid < CAND) {
        float hh = sums[tid * 11];
        float accv = 0.f;
#pragma unroll
        for (int c = 0; c < 10; ++c) { float d = sums[tid * 11 + 1 + c]; accv += (d * d) / hh; }
        v = accv / 10.0f;
        bi = tid;
      }
      sv[tid] = v; si[tid] = bi;
      __syncthreads();
      for (int s2 = 128; s2 > 0; s2 >>= 1) {
        if (tid < s2) {
          float v2 = sv[tid + s2]; int i2 = si[tid + s2];
          if (v2 > sv[tid] || (v2 == sv[tid] && i2 < si[tid])) { sv[tid] = v2; si[tid] = i2; }
        }
        __syncthreads();
      }
      int best = si[0];
      if (tid == 0) *ibest_g = best;
      for (int i = tid; i < DIM; i += 256) outW[(size_t)i * KMAX + k] = Wr[(size_t)i * CAND + best];
      if (tid == 0) outb[k] = br[best];
    }
    gbar(bar, &lgen);

    // ================= R1: r1[j] = Q[:,j].h_c (block j<k); block k copies H col =================
    {
      int best = *ibest_g;
      const float* hc = h_col + (size_t)best * NROWS;
      if (b == k) {
        for (int i = tid; i < NROWS; i += 256)
          Hm[(size_t)k * NROWS + i] = hc[i];
      } else if (b < k) {
        float local = 0.f;
        for (int i = tid; i < NROWS; i += 256)
          local = fmaf(Qm[(size_t)b * NROWS + i], hc[i], local);
        local += __shfl_xor(local, 32); local += __shfl_xor(local, 16);
        local += __shfl_xor(local, 8);  local += __shfl_xor(local, 4);
        local += __shfl_xor(local, 2);  local += __shfl_xor(local, 1);
        float* wred = smem;
        int wid = tid >> 6, lane = tid & 63;
        if (lane == 0) wred[wid] = local;
        __syncthreads();
        if (tid == 0) r1g[b] = wred[0] + wred[1] + wred[2] + wred[3];
      }
    }
    gbar(bar, &lgen);

    // ================= T: t = h_c - Q r1; partials =================
    {
      float* r1s = smem;   // [KMAX]
      for (int jj = tid; jj < k; jj += 256) r1s[jj] = r1g[jj];
      __syncthreads();
      if (tid < 64) {
        int row = b * 64 + tid;
        float tval = 0.f, hc = 0.f, h0 = 0.f;
        float yv[10];
#pragma unroll
        for (int c = 0; c < 10; ++c) yv[c] = 0.f;
        if (row < NROWS) {
          hc = Hm[(size_t)k * NROWS + row];
          float s = 0.f;
          for (int jj = 0; jj < k; ++jj) s = fmaf(Qm[(size_t)jj * NROWS + row], r1s[jj], s);
          tval = hc - s;
          Qm[(size_t)k * NROWS + row] = tval;
#pragma unroll
          for (int c = 0; c < 10; ++c) yv[c] = Y[(size_t)row * MOUT + c];
          if (k == 1) h0 = Hm[row];
        }
        float p[23];
        p[0] = tval * tval;
#pragma unroll
        for (int c = 0; c < 10; ++c) p[1 + c] = tval * yv[c];
        p[11] = hc * hc;
        p[12] = h0 * hc;
#pragma unroll
        for (int c = 0; c < 10; ++c) p[13 + c] = hc * yv[c];
#pragma unroll
        for (int c = 0; c < 23; ++c) {
          float v = p[c];
          v += __shfl_xor(v, 32); v += __shfl_xor(v, 16); v += __shfl_xor(v, 8);
          v += __shfl_xor(v, 4);  v += __shfl_xor(v, 2);  v += __shfl_xor(v, 1);
          p[c] = v;
        }
        if (tid == 0) {
#pragma unroll
          for (int c = 0; c < 23; ++c) part2t[(size_t)c * NBLK + b] = p[c];
        }
      }
    }
    gbar(bar, &lgen);

    // ================= F: finalize r2/R/QT, solve beta (block 0) =================
    if (b == 0) {
      float* vals = smem;      // [23]
      float* bsh = smem2;      // [KMAX][10]
      if (tid < 23) {
        float s = 0.f;
        const float* p = part2t + (size_t)tid * NBLK;
        for (int b2 = 0; b2 < NBLK; ++b2) s += p[b2];
        vals[tid] = s;
      }
      __syncthreads();
      float r2 = sqrtf(vals[0]);
      if (tid < k) Rm[tid * KMAX + k] = r1g[tid];
      if (tid == 0) { Rm[k * KMAX + k] = r2; scal[0] = r2; }
      if (tid < 10) QT[k * 10 + tid] = vals[1 + tid] / r2;
      if (k == 0 && tid < 11) scal[1 + tid] = vals[tid];
      __syncthreads();
      if (k == 0) {
        if (tid < 10) outBeta[tid] = (1.0f / vals[0]) * vals[1 + tid];
      } else if (k == 1) {
        if (tid < 10) {
          float g00 = scal[1], g0y = scal[2 + tid];
          float s11 = vals[11], s01 = vals[12], s1y = vals[13 + tid];
          float det = g00 * s11 - s01 * s01;
          float i00 = s11 / det, i01 = -s01 / det, i11 = g00 / det;
          outBeta[tid]      = i00 * g0y + i01 * s1y;
          outBeta[10 + tid] = i01 * g0y + i11 * s1y;
        }
      } else {
        if (tid < 10) {
          for (int row = k; row >= 0; --row) {
            float s = QT[row * 10 + tid];
            for (int jj = row + 1; jj <= k; ++jj) s = fmaf(-Rm[row * KMAX + jj], bsh[jj * 10 + tid], s);
            float bv = s / Rm[row * KMAX + row];
            bsh[row * 10 + tid] = bv;
            outBeta[row * 10 + tid] = bv;
          }
        }
      }
    }
    gbar(bar, &lgen);

    // ================= U: normalize q, e = Y - H beta; gen W for k+1 =================
    {
      for (int idx = tid; idx < (k + 1) * MOUT; idx += 256) smem2[idx] = outBeta[idx];
      __syncthreads();
      float r2v = scal[0];
      if (tid < 64) {
        int row = b * 64 + tid;
        if (row < NROWS) {
          Qm[(size_t)k * NROWS + row] = Qm[(size_t)k * NROWS + row] / r2v;
          float s[10];
#pragma unroll
          for (int c = 0; c < 10; ++c) s[c] = 0.f;
          for (int j = 0; j <= k; ++j) {
            float hv = Hm[(size_t)j * NROWS + row];
#pragma unroll
            for (int c = 0; c < 10; ++c) s[c] = fmaf(hv, smem2[j * 10 + c], s[c]);
          }
#pragma unroll
          for (int c = 0; c < 10; ++c) e[(size_t)row * MOUT + c] = Y[(size_t)row * MOUT + c] - s[c];
        }
      }
      if (k + 1 < KMAX) {
        uint32_t kw0, kw1, kb0, kb1;
        split3(key0, key1, kw0, kw1, kb0, kb1);
        gen_wb(b, tid, kw0, kw1, kb0, kb1, Wr, br);
      }
    }
    gbar(bar, &lgen);
  }
}

// ---------------- host ----------------
extern "C" void kernel_launch(void* const* d_in, const int* in_sizes, int n_in,
                              void* d_out, int out_size, void* d_ws, size_t ws_size,
                              hipStream_t stream) {
  const float* X = (const float*)d_in[0];
  const float* Y = (const float*)d_in[1];
  float* out = (float*)d_out;
  float* outW    = out;
  float* outb    = out + (size_t)DIM * KMAX;
  float* outBeta = outb + KMAX;

  float* ws = (float*)d_ws;
  size_t off = 0;
  float* h_col = ws + off; off += (size_t)NROWS * CAND;
  float* Wr    = ws + off; off += TOT_W;
  float* br    = ws + off; off += 256;
  float* e     = ws + off; off += (size_t)NROWS * MOUT;
  float* Hm    = ws + off; off += (size_t)KMAX * NROWS;
  float* Qm    = ws + off; off += (size_t)KMAX * NROWS;
  float* Rm    = ws + off; off += (size_t)KMAX * KMAX;
  float* QT    = ws + off; off += (size_t)KMAX * MOUT;
  float* r1g   = ws + off; off += KMAX;
  float* part1t = ws + off; off += (size_t)CAND * 11 * NBLK;
  float* part2t = ws + off; off += (size_t)23 * NBLK;
  float* scal  = ws + off; off += 16;
  unsigned* bar = (unsigned*)(ws + off); off += 16;

  init_bar_kern<<<1, 64, 0, stream>>>(bar);
  scn_mega<<<NBLK, 256, 0, stream>>>(X, Y, outW, outb, outBeta,
                                     h_col, Wr, br, e, Hm, Qm,
                                     Rm, QT, r1g, part1t, part2t, scal, bar);
}

// Round 6
// 19547.531 us; speedup vs baseline: 2.7122x; 2.7122x over previous
//
#include <hip/hip_runtime.h>
#include <cstdint>

#define NROWS 10000
#define DIM   784
#define CAND  150
#define MOUT  10
#define KMAX  64
#define TOT_W 117600   // DIM*CAND
#define TOT_B 150
#define BR 64          // rows per GEMM block
#define BC 160         // padded candidate cols
#define KT 16          // k tile
#define NBLK 157       // ceil(10000/64)
#define NB256 40       // ceil(10000/256)

// ---------------- Threefry-2x32 (exact JAX partitionable semantics) ----------------
#define RND_(r) { x0 += x1; x1 = (x1 << r) | (x1 >> (32 - r)); x1 ^= x0; }

__device__ __host__ inline void threefry2x32(uint32_t k0, uint32_t k1,
                                             uint32_t c0, uint32_t c1,
                                             uint32_t* o0, uint32_t* o1) {
  uint32_t ks2 = 0x1BD11BDAu ^ k0 ^ k1;
  uint32_t x0 = c0 + k0, x1 = c1 + k1;
  RND_(13) RND_(15) RND_(26) RND_(6)
  x0 += k1;  x1 += ks2 + 1u;
  RND_(17) RND_(29) RND_(16) RND_(24)
  x0 += ks2; x1 += k0 + 2u;
  RND_(13) RND_(15) RND_(26) RND_(6)
  x0 += k0;  x1 += k1 + 3u;
  RND_(17) RND_(29) RND_(16) RND_(24)
  x0 += k1;  x1 += ks2 + 4u;
  RND_(13) RND_(15) RND_(26) RND_(6)
  x0 += ks2; x1 += k0 + 5u;
  *o0 = x0; *o1 = x1;
}

__device__ inline float uni01(uint32_t bits) {
  uint32_t fb = (bits >> 9) | 0x3F800000u;
  return __uint_as_float(fb) - 1.0f;
}

__device__ inline float scale_of(int j) {
  return (j < 50) ? 0.5f : ((j < 100) ? 1.0f : 5.0f);
}

// ---------------- kernels ----------------
// e = Y; zero the qr_tf done-counter (handles 0xAA poison each call)
__global__ __launch_bounds__(256) void init_kern(const float* __restrict__ Y, float* __restrict__ e,
                                                 unsigned* __restrict__ counter) {
  int i = blockIdx.x * 256 + threadIdx.x;
  if (i < NROWS * MOUT) e[i] = Y[i];
  if (i == 0) *counter = 0u;
}

__global__ __launch_bounds__(256) void gen_rand_kern(float* __restrict__ Wr, float* __restrict__ br,
                                                     uint32_t kw0, uint32_t kw1,
                                                     uint32_t kb0, uint32_t kb1) {
  int f = blockIdx.x * 256 + threadIdx.x;
  if (f < TOT_W) {
    uint32_t o0, o1;
    threefry2x32(kw0, kw1, 0u, (uint32_t)f, &o0, &o1);
    float u = uni01(o0 ^ o1);
    int j = f % CAND;
    Wr[f] = scale_of(j) * (2.0f * u - 1.0f);
  } else if (f < TOT_W + TOT_B) {
    int g = f - TOT_W;
    uint32_t o0, o1;
    threefry2x32(kb0, kb1, 0u, (uint32_t)g, &o0, &o1);
    float u = uni01(o0 ^ o1);
    br[g] = scale_of(g) * (2.0f * u - 1.0f);
  }
}

// h = sigmoid(X@W + b), h column-major; partials -> part1t[idx][block] (transposed)
__global__ __launch_bounds__(256) void gemm_h_kern(const float* __restrict__ X, const float* __restrict__ e,
                                                   const float* __restrict__ Wr, const float* __restrict__ br_,
                                                   float* __restrict__ h_col, float* __restrict__ part1t) {
  __shared__ __align__(16) float smem[7040];
  __shared__ float et[BR][MOUT];
  float* Xt = smem;            // [KT][BR]
  float* Wt = smem + 1024;     // [KT][BC]
  float* red = smem;           // [4][BC*11] aliased after compute

  int tid = threadIdx.x;
  int ty = tid >> 5, tx = tid & 31;
  int row0 = blockIdx.x * BR;
  int nr = NROWS - row0; if (nr > BR) nr = BR;
  bool full = (nr == BR);

  for (int idx = tid; idx < BR * MOUT; idx += 256) {
    int r = idx / MOUT, c = idx - r * MOUT;
    et[r][c] = (row0 + r < NROWS) ? e[(size_t)(row0 + r) * MOUT + c] : 0.f;
  }

  float bbv[5];
#pragma unroll
  for (int cl = 0; cl < 5; ++cl) {
    int c = tx + 32 * cl;
    bbv[cl] = (c < CAND) ? br_[c] : 0.f;
  }

  float acc[8][5];
#pragma unroll
  for (int r = 0; r < 8; ++r)
#pragma unroll
    for (int cl = 0; cl < 5; ++cl) acc[r][cl] = 0.f;

  int rstage = tid >> 2;
  int qg = (tid & 3) * 4;
  int rclamp = rstage < nr ? rstage : nr - 1;
  const float* Xrow = X + (size_t)(row0 + rclamp) * DIM;

  for (int kk = 0; kk < DIM; kk += KT) {
    __syncthreads();
    float4 xv4 = *(const float4*)(Xrow + kk + qg);
    Xt[(qg + 0) * BR + rstage] = xv4.x;
    Xt[(qg + 1) * BR + rstage] = xv4.y;
    Xt[(qg + 2) * BR + rstage] = xv4.z;
    Xt[(qg + 3) * BR + rstage] = xv4.w;
    for (int idx = tid; idx < KT * BC; idx += 256) {
      int q = idx / BC, c = idx - q * BC;
      Wt[idx] = (c < CAND) ? Wr[(size_t)(kk + q) * CAND + c] : 0.f;
    }
    __syncthreads();
#pragma unroll
    for (int q = 0; q < KT; ++q) {
      float xv[8];
      *(float4*)&xv[0] = *(const float4*)&Xt[q * BR + ty * 8];
      *(float4*)&xv[4] = *(const float4*)&Xt[q * BR + ty * 8 + 4];
      float wv[5];
#pragma unroll
      for (int cl = 0; cl < 5; ++cl) wv[cl] = Wt[q * BC + tx + 32 * cl];
#pragma unroll
      for (int r = 0; r < 8; ++r)
#pragma unroll
        for (int cl = 0; cl < 5; ++cl)
          acc[r][cl] = fmaf(xv[r], wv[cl], acc[r][cl]);
    }
  }

  __syncthreads();

#pragma unroll
  for (int cl = 0; cl < 5; ++cl) {
    int c = tx + 32 * cl;
    float hv[8];
#pragma unroll
    for (int r = 0; r < 8; ++r)
      hv[r] = 1.0f / (1.0f + expf(-(acc[r][cl] + bbv[cl])));
    if (c < CAND) {
      float* dst = h_col + (size_t)c * NROWS + row0 + ty * 8;
      if (full) {
        float4 a = {hv[0], hv[1], hv[2], hv[3]};
        float4 b4 = {hv[4], hv[5], hv[6], hv[7]};
        *(float4*)dst = a;
        *(float4*)(dst + 4) = b4;
      } else {
#pragma unroll
        for (int r = 0; r < 8; ++r)
          if (ty * 8 + r < nr) dst[r] = hv[r];
      }
    }
    float hh = 0.f, eth[10];
#pragma unroll
    for (int j = 0; j < 10; ++j) eth[j] = 0.f;
#pragma unroll
    for (int r = 0; r < 8; ++r) {
      if (full || ty * 8 + r < nr) {
        hh = fmaf(hv[r], hv[r], hh);
#pragma unroll
        for (int j = 0; j < 10; ++j) eth[j] = fmaf(et[ty * 8 + r][j], hv[r], eth[j]);
      }
    }
    hh += __shfl_xor(hh, 32);
#pragma unroll
    for (int j = 0; j < 10; ++j) eth[j] += __shfl_xor(eth[j], 32);
    if (!(ty & 1) && c < CAND) {
      float* dstr = red + (ty >> 1) * 1760 + c * 11;
      dstr[0] = hh;
#pragma unroll
      for (int j = 0; j < 10; ++j) dstr[1 + j] = eth[j];
    }
  }
  __syncthreads();
  for (int idx = tid; idx < CAND * 11; idx += 256) {
    float s = red[idx] + red[1760 + idx] + red[3520 + idx] + red[5280 + idx];
    part1t[(size_t)idx * NBLK + blockIdx.x] = s;
  }
}

// 150 blocks x 64 threads: block c reduces its 11 partials over 157 blocks -> v[c]
__global__ __launch_bounds__(64) void score_v_kern(const float* __restrict__ part1t,
                                                   float* __restrict__ vglob) {
  int c = blockIdx.x, tid = threadIdx.x;
  float sums[11];
#pragma unroll
  for (int j = 0; j < 11; ++j) {
    const float* p = part1t + (size_t)(c * 11 + j) * NBLK;
    float s = (tid < NBLK) ? p[tid] : 0.f;
    if (tid + 64 < NBLK) s += p[tid + 64];
    if (tid + 128 < NBLK) s += p[tid + 128];
    s += __shfl_xor(s, 32); s += __shfl_xor(s, 16); s += __shfl_xor(s, 8);
    s += __shfl_xor(s, 4);  s += __shfl_xor(s, 2);  s += __shfl_xor(s, 1);
    sums[j] = s;
  }
  if (tid == 0) {
    float hh = sums[0];
    float accv = 0.f;
#pragma unroll
    for (int j = 0; j < 10; ++j) { float d = sums[1 + j]; accv += (d * d) / hh; }
    vglob[c] = accv / 10.0f;
  }
}

// 1 block: argmax (first-index tie-break), record W col / b / ibest
__global__ __launch_bounds__(256) void pick_kern(const float* __restrict__ vglob,
                                                 const float* __restrict__ Wr, const float* __restrict__ br,
                                                 float* __restrict__ outW, float* __restrict__ outb,
                                                 int* __restrict__ ibest, int k) {
  __shared__ float sv[256];
  __shared__ int   si[256];
  __shared__ int   sbest;
  int tid = threadIdx.x;
  float v = -INFINITY; int bi = 0x7FFFFFFF;
  if (tid < CAND) { v = vglob[tid]; bi = tid; }
  sv[tid] = v; si[tid] = bi;
  __syncthreads();
  for (int s2 = 128; s2 > 0; s2 >>= 1) {
    if (tid < s2) {
      float v2 = sv[tid + s2]; int i2 = si[tid + s2];
      if (v2 > sv[tid] || (v2 == sv[tid] && i2 < si[tid])) { sv[tid] = v2; si[tid] = i2; }
    }
    __syncthreads();
  }
  if (tid == 0) { sbest = si[0]; *ibest = si[0]; }
  __syncthreads();
  int best = sbest;
  for (int i = tid; i < DIM; i += 256) outW[(size_t)i * KMAX + k] = Wr[(size_t)i * CAND + best];
  if (tid == 0) outb[k] = br[best];
}

// block j<k: r1[j] = Q[:,j].h_c ; block j==k: copy H[:,k] = h_col[:,best]
__global__ __launch_bounds__(256) void qr_r1_kern(const float* __restrict__ h_col, float* __restrict__ Hm,
                                                  const float* __restrict__ Qm, float* __restrict__ r1g,
                                                  const int* __restrict__ ibest, int k) {
  int j = blockIdx.x, tid = threadIdx.x;
  int best = *ibest;
  const float* hc = h_col + (size_t)best * NROWS;
  if (j == k) {
    for (int i = tid; i < NROWS; i += 256)
      Hm[(size_t)k * NROWS + i] = hc[i];
  } else {
    float local = 0.f;
    for (int i = tid; i < NROWS; i += 256)
      local = fmaf(Qm[(size_t)j * NROWS + i], hc[i], local);
    local += __shfl_xor(local, 32); local += __shfl_xor(local, 16);
    local += __shfl_xor(local, 8);  local += __shfl_xor(local, 4);
    local += __shfl_xor(local, 2);  local += __shfl_xor(local, 1);
    __shared__ float wred[4];
    int wid = tid >> 6, lane = tid & 63;
    if (lane == 0) wred[wid] = local;
    __syncthreads();
    if (tid == 0) r1g[j] = wred[0] + wred[1] + wred[2] + wred[3];
  }
}

// t = h_c - Q r1; partials; LAST block finalizes r2/R/QT and solves beta.
__global__ __launch_bounds__(256) void qr_tf_kern(const float* __restrict__ Hm, float* __restrict__ Qm,
                                                  const float* __restrict__ r1g, const float* __restrict__ Y,
                                                  float* __restrict__ part2, float* __restrict__ Rm,
                                                  float* __restrict__ QT, float* __restrict__ scal,
                                                  float* __restrict__ outBeta, unsigned* __restrict__ counter,
                                                  int k) {
  __shared__ float r1s[KMAX];
  int tid = threadIdx.x;
  for (int jj = tid; jj < k; jj += 256) r1s[jj] = r1g[jj];
  __syncthreads();

  int i = blockIdx.x * 256 + tid;
  float tval = 0.f, hc = 0.f, h0 = 0.f;
  float yv[10];
#pragma unroll
  for (int c = 0; c < 10; ++c) yv[c] = 0.f;

  if (i < NROWS) {
    hc = Hm[(size_t)k * NROWS + i];
    float s = 0.f;
    for (int jj = 0; jj < k; ++jj) s = fmaf(Qm[(size_t)jj * NROWS + i], r1s[jj], s);
    tval = hc - s;
    Qm[(size_t)k * NROWS + i] = tval;
#pragma unroll
    for (int c = 0; c < 10; ++c) yv[c] = Y[(size_t)i * 10 + c];
    if (k == 1) h0 = Hm[i];
  }

  float p[23];
  p[0] = tval * tval;
#pragma unroll
  for (int c = 0; c < 10; ++c) p[1 + c] = tval * yv[c];
  p[11] = hc * hc;
  p[12] = h0 * hc;
#pragma unroll
  for (int c = 0; c < 10; ++c) p[13 + c] = hc * yv[c];

  __shared__ float wred[4][23];
  int lane = tid & 63, wid = tid >> 6;
#pragma unroll
  for (int c = 0; c < 23; ++c) {
    float v = p[c];
    v += __shfl_xor(v, 32); v += __shfl_xor(v, 16); v += __shfl_xor(v, 8);
    v += __shfl_xor(v, 4);  v += __shfl_xor(v, 2);  v += __shfl_xor(v, 1);
    if (lane == 0) wred[wid][c] = v;
  }
  __syncthreads();
  if (tid < 23) part2[blockIdx.x * 23 + tid] = wred[0][tid] + wred[1][tid] + wred[2][tid] + wred[3][tid];

  // ---- last-block finalize ----
  __syncthreads();
  __shared__ int lastFlag;
  if (tid == 0) {
    __threadfence();
    unsigned d = __hip_atomic_fetch_add(counter, 1u, __ATOMIC_ACQ_REL, __HIP_MEMORY_SCOPE_AGENT);
    lastFlag = (d == NB256 - 1) ? 1 : 0;
  }
  __syncthreads();
  if (!lastFlag) return;
  if (tid == 0) { __threadfence(); *counter = 0u; }
  __syncthreads();

  __shared__ float vals[23];
  __shared__ float bsh[KMAX * 10];
  if (tid < 23) {
    float s = 0.f;
    for (int b = 0; b < NB256; ++b) s += part2[b * 23 + tid];
    vals[tid] = s;
  }
  __syncthreads();
  float r2 = sqrtf(vals[0]);
  if (tid < k) Rm[tid * KMAX + k] = r1g[tid];
  if (tid == 0) { Rm[k * KMAX + k] = r2; scal[0] = r2; }
  if (tid < 10) QT[k * 10 + tid] = vals[1 + tid] / r2;
  if (k == 0 && tid < 11) scal[1 + tid] = vals[tid];
  __syncthreads();
  if (k == 0) {
    if (tid < 10) outBeta[tid] = (1.0f / vals[0]) * vals[1 + tid];
  } else if (k == 1) {
    if (tid < 10) {
      float g00 = scal[1], g0y = scal[2 + tid];
      float s11 = vals[11], s01 = vals[12], s1y = vals[13 + tid];
      float det = g00 * s11 - s01 * s01;
      float i00 = s11 / det, i01 = -s01 / det, i11 = g00 / det;
      outBeta[tid]      = i00 * g0y + i01 * s1y;
      outBeta[10 + tid] = i01 * g0y + i11 * s1y;
    }
  } else {
    if (tid < 10) {
      for (int row = k; row >= 0; --row) {
        float s = QT[row * 10 + tid];
        for (int jj = row + 1; jj <= k; ++jj) s = fmaf(-Rm[row * KMAX + jj], bsh[jj * 10 + tid], s);
        float bv = s / Rm[row * KMAX + row];
        bsh[row * 10 + tid] = bv;
        outBeta[row * 10 + tid] = bv;
      }
    }
  }
}

// blocks 0..39: normalize q, e = Y - H beta ; blocks 40+: gen W/b for next step
__global__ __launch_bounds__(256) void upd_gen_kern(const float* __restrict__ Hm, float* __restrict__ Qm,
                                                    const float* __restrict__ Y, const float* __restrict__ beta,
                                                    float* __restrict__ e, const float* __restrict__ scal,
                                                    float* __restrict__ Wr, float* __restrict__ br,
                                                    uint32_t kw0, uint32_t kw1, uint32_t kb0, uint32_t kb1,
                                                    int k) {
  int b = blockIdx.x, tid = threadIdx.x;
  if (b < NB256) {
    int i = b * 256 + tid;
    if (i >= NROWS) return;
    float r2 = scal[0];
    Qm[(size_t)k * NROWS + i] = Qm[(size_t)k * NROWS + i] / r2;
    float s[10];
#pragma unroll
    for (int c = 0; c < 10; ++c) s[c] = 0.f;
    for (int j = 0; j <= k; ++j) {
      float hv = Hm[(size_t)j * NROWS + i];
#pragma unroll
      for (int c = 0; c < 10; ++c) s[c] = fmaf(hv, beta[j * 10 + c], s[c]);
    }
#pragma unroll
    for (int c = 0; c < 10; ++c) e[(size_t)i * 10 + c] = Y[(size_t)i * 10 + c] - s[c];
  } else {
    int f = (b - NB256) * 256 + tid;
    if (f < TOT_W) {
      uint32_t o0, o1;
      threefry2x32(kw0, kw1, 0u, (uint32_t)f, &o0, &o1);
      float u = uni01(o0 ^ o1);
      int j = f % CAND;
      Wr[f] = scale_of(j) * (2.0f * u - 1.0f);
    } else if (f < TOT_W + TOT_B) {
      int g = f - TOT_W;
      uint32_t o0, o1;
      threefry2x32(kb0, kb1, 0u, (uint32_t)g, &o0, &o1);
      float u = uni01(o0 ^ o1);
      br[g] = scale_of(g) * (2.0f * u - 1.0f);
    }
  }
}

// ---------------- host ----------------
extern "C" void kernel_launch(void* const* d_in, const int* in_sizes, int n_in,
                              void* d_out, int out_size, void* d_ws, size_t ws_size,
                              hipStream_t stream) {
  const float* X = (const float*)d_in[0];
  const float* Y = (const float*)d_in[1];
  float* out = (float*)d_out;
  float* outW    = out;
  float* outb    = out + (size_t)DIM * KMAX;
  float* outBeta = outb + KMAX;

  float* ws = (float*)d_ws;
  size_t off = 0;
  float* h_col = ws + off; off += (size_t)NROWS * CAND;
  float* Wr    = ws + off; off += TOT_W;
  float* br    = ws + off; off += 256;
  float* e     = ws + off; off += (size_t)NROWS * MOUT;
  float* Hm    = ws + off; off += (size_t)KMAX * NROWS;
  float* Qm    = ws + off; off += (size_t)KMAX * NROWS;
  float* Rm    = ws + off; off += (size_t)KMAX * KMAX;
  float* QT    = ws + off; off += (size_t)KMAX * MOUT;
  float* r1g   = ws + off; off += KMAX;
  float* part1t = ws + off; off += (size_t)CAND * 11 * NBLK;
  float* part2  = ws + off; off += (size_t)NB256 * 23;
  float* vglob  = ws + off; off += 256;
  float* scal   = ws + off; off += 16;
  int*   ibest  = (int*)(ws + off); off += 4;
  unsigned* counter = (unsigned*)(ws + off); off += 4;

  // precompute key chain on host (bit-exact JAX split semantics)
  uint32_t kws0[KMAX], kws1[KMAX], kbs0[KMAX], kbs1[KMAX];
  uint32_t key0 = 0u, key1 = 42u;
  for (int k = 0; k < KMAX; ++k) {
    uint32_t o0[3], o1[3];
    for (int t = 0; t < 3; ++t)
      threefry2x32(key0, key1, 0u, (uint32_t)t, &o0[t], &o1[t]);
    kws0[k] = o0[1]; kws1[k] = o1[1]; kbs0[k] = o0[2]; kbs1[k] = o1[2];
    key0 = o0[0]; key1 = o1[0];
  }

  init_kern<<<(NROWS * MOUT + 255) / 256, 256, 0, stream>>>(Y, e, counter);
  gen_rand_kern<<<(TOT_W + TOT_B + 255) / 256, 256, 0, stream>>>(Wr, br, kws0[0], kws1[0], kbs0[0], kbs1[0]);

  for (int k = 0; k < KMAX; ++k) {
    gemm_h_kern<<<NBLK, 256, 0, stream>>>(X, e, Wr, br, h_col, part1t);
    score_v_kern<<<CAND, 64, 0, stream>>>(part1t, vglob);
    pick_kern<<<1, 256, 0, stream>>>(vglob, Wr, br, outW, outb, ibest, k);
    qr_r1_kern<<<k + 1, 256, 0, stream>>>(h_col, Hm, Qm, r1g, ibest, k);
    qr_tf_kern<<<NB256, 256, 0, stream>>>(Hm, Qm, r1g, Y, part2, Rm, QT, scal, outBeta, counter, k);
    bool genNext = (k + 1 < KMAX);
    int nblocks = genNext ? (NB256 + (TOT_W + TOT_B + 255) / 256) : NB256;
    int kn = genNext ? (k + 1) : 0;
    upd_gen_kern<<<nblocks, 256, 0, stream>>>(Hm, Qm, Y, outBeta, e, scal, Wr, br,
                                              kws0[kn], kws1[kn], kbs0[kn], kbs1[kn], k);
  }
}